// Round 8
// baseline (597.832 us; speedup 1.0000x reference)
//
#include <hip/hip_runtime.h>
#include <math.h>

#define N_NODES 100000
#define N_EDGES 1600000
#define IN_FEATS 128
#define H_FEATS 64
#define SCAN_BLOCKS 391   // ceil(100000/256)

// ---------------- int degree histogram ----------------
__global__ __launch_bounds__(256) void hist_kernel(const int* __restrict__ dst,
                                                   int* __restrict__ degi) {
    int tid = blockIdx.x * 256 + threadIdx.x;
    int stride = gridDim.x * 256;
    for (int e = tid; e < N_EDGES; e += stride)
        atomicAdd(&degi[dst[e]], 1);
}

// degi -> dinv = 1/sqrt(max(deg,1))
__global__ __launch_bounds__(256) void dinv_kernel(const int* __restrict__ degi,
                                                   float* __restrict__ dinv) {
    int i = blockIdx.x * 256 + threadIdx.x;
    if (i < N_NODES) dinv[i] = rsqrtf(fmaxf((float)degi[i], 1.0f));
}

// ---------------- 3-kernel exclusive scan of degi -> rowp ----------------
__global__ __launch_bounds__(256) void scan1_kernel(const int* __restrict__ degi,
                                                    int* __restrict__ rowp,
                                                    int* __restrict__ bsums) {
    __shared__ int tmp[256];
    int i = blockIdx.x * 256 + threadIdx.x;
    int v = (i < N_NODES) ? degi[i] : 0;
    tmp[threadIdx.x] = v;
    __syncthreads();
    #pragma unroll
    for (int off = 1; off < 256; off <<= 1) {
        int t = (threadIdx.x >= off) ? tmp[threadIdx.x - off] : 0;
        __syncthreads();
        tmp[threadIdx.x] += t;
        __syncthreads();
    }
    if (i < N_NODES) rowp[i] = tmp[threadIdx.x] - v;
    if (threadIdx.x == 255) bsums[blockIdx.x] = tmp[255];
}

__global__ __launch_bounds__(512) void scan2_kernel(int* __restrict__ bsums) {
    __shared__ int tmp[512];
    int t = threadIdx.x;
    int v = (t < SCAN_BLOCKS) ? bsums[t] : 0;
    tmp[t] = v;
    __syncthreads();
    #pragma unroll
    for (int off = 1; off < 512; off <<= 1) {
        int x = (t >= off) ? tmp[t - off] : 0;
        __syncthreads();
        tmp[t] += x;
        __syncthreads();
    }
    if (t < SCAN_BLOCKS) bsums[t] = tmp[t] - v;
}

__global__ __launch_bounds__(256) void scan3_kernel(int* __restrict__ rowp,
                                                    const int* __restrict__ bsums) {
    int i = blockIdx.x * 256 + threadIdx.x;
    if (i < N_NODES) rowp[i] += bsums[blockIdx.x];
    if (i == N_NODES) rowp[N_NODES] = N_EDGES;
}

// ---------------- fill CSR slots: single packed 8B write per edge ----------------
__global__ __launch_bounds__(256) void fill_kernel(const int* __restrict__ src,
                                                   const int* __restrict__ dst,
                                                   const int* __restrict__ rowp,
                                                   const float* __restrict__ dinv,
                                                   int* __restrict__ cursor,
                                                   int2* __restrict__ epack) {
    int tid = blockIdx.x * 256 + threadIdx.x;
    int stride = gridDim.x * 256;
    for (int e = tid; e < N_EDGES; e += stride) {
        int d = dst[e];
        int s = src[e];
        int slot = rowp[d] + atomicAdd(&cursor[d], 1);
        epack[slot] = make_int2(s, __float_as_int(dinv[s]));
    }
}

// ---------------- Weff[k][i][j] = sum_c thetas[c][k] * Wm1[c*64+i][j] ----------------
__global__ __launch_bounds__(256) void weff_kernel(const float* __restrict__ thetas,
                                                   const float* __restrict__ Wm1,
                                                   float* __restrict__ Weff) {
    int t = blockIdx.x * 256 + threadIdx.x;  // 16384 total
    int k = t >> 12, ij = t & 4095, i = ij >> 6, j = ij & 63;
    float acc = 0.f;
    #pragma unroll
    for (int c = 0; c < 3; ++c)
        acc = fmaf(thetas[c * 4 + k], Wm1[(c * 64 + i) * 64 + j], acc);
    Weff[t] = acc;
}

// ---------------- trunk: h = relu(relu(X@W1+b1)@W2+b2);  T0 = h@Weff[3] ----------------
// 64 rows/block, 4 batches of 16. K split across 4 waves; weights in VGPRs;
// activations LDS-staged flat (conflict-free); 3 GEMM stages.
__global__ __launch_bounds__(256) void trunk_kernel(
    const float* __restrict__ X, const float* __restrict__ W1, const float* __restrict__ b1,
    const float* __restrict__ W2, const float* __restrict__ b2,
    const float* __restrict__ Weff3, float* __restrict__ H, float* __restrict__ T0)
{
    __shared__ float stage[16][IN_FEATS];   // 8 KB = 512 float4
    __shared__ float part[4][16][64];       // 16 KB
    __shared__ float h1s[16][64];           // 4 KB (reused as h2 for stage 3)
    int t = threadIdx.x;
    int wv = __builtin_amdgcn_readfirstlane(t >> 6);
    int lane = t & 63;
    float w1r[32], w2r[16], w3r[16];
    #pragma unroll
    for (int i = 0; i < 32; ++i) w1r[i] = W1[(wv * 32 + i) * 64 + lane];
    #pragma unroll
    for (int i = 0; i < 16; ++i) w2r[i] = W2[(wv * 16 + i) * 64 + lane];
    #pragma unroll
    for (int i = 0; i < 16; ++i) w3r[i] = Weff3[(wv * 16 + i) * 64 + lane];
    float b1v = b1[lane], b2v = b2[lane];
    int srow = t >> 5, sf4 = t & 31;
    float4* st4 = (float4*)stage;

    for (int batch = 0; batch < 4; ++batch) {
        int row0 = blockIdx.x * 64 + batch * 16;
        #pragma unroll
        for (int p = 0; p < 2; ++p) {
            int row = row0 + srow + 8 * p;
            if (row >= N_NODES) row = N_NODES - 1;
            st4[t + 256 * p] =
                ((const float4*)(X + (size_t)row * IN_FEATS))[sf4];
        }
        __syncthreads();
        // stage 1
        float acc[16];
        #pragma unroll
        for (int r = 0; r < 16; ++r) {
            const float4* xb = (const float4*)&stage[r][wv * 32];   // uniform -> broadcast
            float a = 0.f, b = 0.f;
            #pragma unroll
            for (int i4 = 0; i4 < 8; i4 += 2) {
                float4 v0 = xb[i4], v1 = xb[i4 + 1];
                a = fmaf(v0.x, w1r[i4 * 4 + 0], a);
                a = fmaf(v0.y, w1r[i4 * 4 + 1], a);
                a = fmaf(v0.z, w1r[i4 * 4 + 2], a);
                a = fmaf(v0.w, w1r[i4 * 4 + 3], a);
                b = fmaf(v1.x, w1r[i4 * 4 + 4], b);
                b = fmaf(v1.y, w1r[i4 * 4 + 5], b);
                b = fmaf(v1.z, w1r[i4 * 4 + 6], b);
                b = fmaf(v1.w, w1r[i4 * 4 + 7], b);
            }
            acc[r] = a + b;
        }
        #pragma unroll
        for (int r = 0; r < 16; ++r) part[wv][r][lane] = acc[r];
        __syncthreads();
        #pragma unroll
        for (int rr = 0; rr < 4; ++rr) {
            int r = wv * 4 + rr;
            float y1 = part[0][r][lane] + part[1][r][lane] +
                       part[2][r][lane] + part[3][r][lane] + b1v;
            h1s[r][lane] = fmaxf(y1, 0.f);
        }
        __syncthreads();
        // stage 2
        float acc2[16];
        #pragma unroll
        for (int r = 0; r < 16; ++r) {
            const float4* xb = (const float4*)&h1s[r][wv * 16];     // uniform -> broadcast
            float a = 0.f, b = 0.f;
            #pragma unroll
            for (int i4 = 0; i4 < 4; i4 += 2) {
                float4 v0 = xb[i4], v1 = xb[i4 + 1];
                a = fmaf(v0.x, w2r[i4 * 4 + 0], a);
                a = fmaf(v0.y, w2r[i4 * 4 + 1], a);
                a = fmaf(v0.z, w2r[i4 * 4 + 2], a);
                a = fmaf(v0.w, w2r[i4 * 4 + 3], a);
                b = fmaf(v1.x, w2r[i4 * 4 + 4], b);
                b = fmaf(v1.y, w2r[i4 * 4 + 5], b);
                b = fmaf(v1.z, w2r[i4 * 4 + 6], b);
                b = fmaf(v1.w, w2r[i4 * 4 + 7], b);
            }
            acc2[r] = a + b;
        }
        __syncthreads();
        #pragma unroll
        for (int r = 0; r < 16; ++r) part[wv][r][lane] = acc2[r];
        __syncthreads();
        // h = relu(stage2) -> H global + h1s (reused) for stage 3
        #pragma unroll
        for (int rr = 0; rr < 4; ++rr) {
            int r = wv * 4 + rr;
            int row = row0 + r;
            float y2 = part[0][r][lane] + part[1][r][lane] +
                       part[2][r][lane] + part[3][r][lane] + b2v;
            y2 = fmaxf(y2, 0.f);
            h1s[r][lane] = y2;
            if (row < N_NODES) H[(size_t)row * 64 + lane] = y2;
        }
        __syncthreads();
        // stage 3: T0 = h @ Weff[3]  (no bias)
        float acc3[16];
        #pragma unroll
        for (int r = 0; r < 16; ++r) {
            const float4* xb = (const float4*)&h1s[r][wv * 16];
            float a = 0.f, b = 0.f;
            #pragma unroll
            for (int i4 = 0; i4 < 4; i4 += 2) {
                float4 v0 = xb[i4], v1 = xb[i4 + 1];
                a = fmaf(v0.x, w3r[i4 * 4 + 0], a);
                a = fmaf(v0.y, w3r[i4 * 4 + 1], a);
                a = fmaf(v0.z, w3r[i4 * 4 + 2], a);
                a = fmaf(v0.w, w3r[i4 * 4 + 3], a);
                b = fmaf(v1.x, w3r[i4 * 4 + 4], b);
                b = fmaf(v1.y, w3r[i4 * 4 + 5], b);
                b = fmaf(v1.z, w3r[i4 * 4 + 6], b);
                b = fmaf(v1.w, w3r[i4 * 4 + 7], b);
            }
            acc3[r] = a + b;
        }
        #pragma unroll
        for (int r = 0; r < 16; ++r) part[wv][r][lane] = acc3[r];
        __syncthreads();
        #pragma unroll
        for (int rr = 0; rr < 4; ++rr) {
            int r = wv * 4 + rr;
            int row = row0 + r;
            float t0 = part[0][r][lane] + part[1][r][lane] +
                       part[2][r][lane] + part[3][r][lane];
            if (row < N_NODES) T0[(size_t)row * 64 + lane] = t0;
        }
        __syncthreads();
    }
}

// ---------------- Horner gather pass: Tnew = L*Tprev + Hf@Weffk ----------------
// L*T = T - dinv[n]*sum_e w_e*T[src_e]. One wave per 8 consecutive nodes;
// Weffk column held in 64 VGPRs (amortized); h-row broadcast via __shfl.
__global__ __launch_bounds__(256) void ghorner_kernel(
    const float* __restrict__ Tprev, const float* __restrict__ Hf,
    const int* __restrict__ rowp, const int2* __restrict__ epack,
    const float* __restrict__ dinv, const float* __restrict__ Weffk,
    float* __restrict__ Tnew)
{
    int wv = __builtin_amdgcn_readfirstlane(threadIdx.x >> 6);
    int lane = threadIdx.x & 63;
    int gw = blockIdx.x * 4 + wv;          // 12500 waves, 8 nodes each
    float wreg[64];
    #pragma unroll
    for (int i = 0; i < 64; ++i) wreg[i] = Weffk[i * 64 + lane];

    for (int u = 0; u < 8; ++u) {
        int wid = gw * 8 + u;              // node id (uniform), < 100000
        int beg = rowp[wid], end = rowp[wid + 1];
        float acc = 0.0f;
        int j = beg;
        for (; j + 7 < end; j += 8) {
            int2 e0 = epack[j],     e1 = epack[j + 1], e2 = epack[j + 2], e3 = epack[j + 3];
            int2 e4 = epack[j + 4], e5 = epack[j + 5], e6 = epack[j + 6], e7 = epack[j + 7];
            float v0 = Tprev[(size_t)e0.x * 64 + lane];
            float v1 = Tprev[(size_t)e1.x * 64 + lane];
            float v2 = Tprev[(size_t)e2.x * 64 + lane];
            float v3 = Tprev[(size_t)e3.x * 64 + lane];
            float v4 = Tprev[(size_t)e4.x * 64 + lane];
            float v5 = Tprev[(size_t)e5.x * 64 + lane];
            float v6 = Tprev[(size_t)e6.x * 64 + lane];
            float v7 = Tprev[(size_t)e7.x * 64 + lane];
            acc = fmaf(v0, __int_as_float(e0.y), acc);
            acc = fmaf(v1, __int_as_float(e1.y), acc);
            acc = fmaf(v2, __int_as_float(e2.y), acc);
            acc = fmaf(v3, __int_as_float(e3.y), acc);
            acc = fmaf(v4, __int_as_float(e4.y), acc);
            acc = fmaf(v5, __int_as_float(e5.y), acc);
            acc = fmaf(v6, __int_as_float(e6.y), acc);
            acc = fmaf(v7, __int_as_float(e7.y), acc);
        }
        for (; j < end; ++j) {
            int2 e = epack[j];
            acc = fmaf(Tprev[(size_t)e.x * 64 + lane], __int_as_float(e.y), acc);
        }
        // GEMV: c = Hf[wid] @ Weffk (column = lane), h row broadcast via shfl
        float hv = Hf[(size_t)wid * 64 + lane];
        float c0 = 0.f, c1 = 0.f;
        #pragma unroll
        for (int i = 0; i < 64; i += 2) {
            c0 = fmaf(__shfl(hv, i),     wreg[i],     c0);
            c1 = fmaf(__shfl(hv, i + 1), wreg[i + 1], c1);
        }
        Tnew[(size_t)wid * 64 + lane] =
            Tprev[(size_t)wid * 64 + lane] - acc * dinv[wid] + c0 + c1;
    }
}

// ---------------- Horner final pass: out = relu(L*Tprev + Hf@Weff0 + bm1)@Wm2 + bm2
__global__ __launch_bounds__(256) void ghfinal_kernel(
    const float* __restrict__ Tprev, const float* __restrict__ Hf,
    const int* __restrict__ rowp, const int2* __restrict__ epack,
    const float* __restrict__ dinv, const float* __restrict__ Weff0,
    const float* __restrict__ Wm2, const float* __restrict__ bm1,
    const float* __restrict__ bm2, float* __restrict__ out)
{
    int wv = __builtin_amdgcn_readfirstlane(threadIdx.x >> 6);
    int lane = threadIdx.x & 63;
    int gw = blockIdx.x * 4 + wv;
    float wreg[64];
    #pragma unroll
    for (int i = 0; i < 64; ++i) wreg[i] = Weff0[i * 64 + lane];
    float b1v = bm1[lane];
    float wm20 = Wm2[lane * 2 + 0], wm21 = Wm2[lane * 2 + 1];
    float bm20 = bm2[0], bm21 = bm2[1];

    for (int u = 0; u < 8; ++u) {
        int wid = gw * 8 + u;
        int beg = rowp[wid], end = rowp[wid + 1];
        float acc = 0.0f;
        int j = beg;
        for (; j + 7 < end; j += 8) {
            int2 e0 = epack[j],     e1 = epack[j + 1], e2 = epack[j + 2], e3 = epack[j + 3];
            int2 e4 = epack[j + 4], e5 = epack[j + 5], e6 = epack[j + 6], e7 = epack[j + 7];
            float v0 = Tprev[(size_t)e0.x * 64 + lane];
            float v1 = Tprev[(size_t)e1.x * 64 + lane];
            float v2 = Tprev[(size_t)e2.x * 64 + lane];
            float v3 = Tprev[(size_t)e3.x * 64 + lane];
            float v4 = Tprev[(size_t)e4.x * 64 + lane];
            float v5 = Tprev[(size_t)e5.x * 64 + lane];
            float v6 = Tprev[(size_t)e6.x * 64 + lane];
            float v7 = Tprev[(size_t)e7.x * 64 + lane];
            acc = fmaf(v0, __int_as_float(e0.y), acc);
            acc = fmaf(v1, __int_as_float(e1.y), acc);
            acc = fmaf(v2, __int_as_float(e2.y), acc);
            acc = fmaf(v3, __int_as_float(e3.y), acc);
            acc = fmaf(v4, __int_as_float(e4.y), acc);
            acc = fmaf(v5, __int_as_float(e5.y), acc);
            acc = fmaf(v6, __int_as_float(e6.y), acc);
            acc = fmaf(v7, __int_as_float(e7.y), acc);
        }
        for (; j < end; ++j) {
            int2 e = epack[j];
            acc = fmaf(Tprev[(size_t)e.x * 64 + lane], __int_as_float(e.y), acc);
        }
        float hv = Hf[(size_t)wid * 64 + lane];
        float c0 = 0.f, c1 = 0.f;
        #pragma unroll
        for (int i = 0; i < 64; i += 2) {
            c0 = fmaf(__shfl(hv, i),     wreg[i],     c0);
            c1 = fmaf(__shfl(hv, i + 1), wreg[i + 1], c1);
        }
        float y = Tprev[(size_t)wid * 64 + lane] - acc * dinv[wid] + c0 + c1 + b1v;
        y = fmaxf(y, 0.f);
        float o0 = y * wm20;
        float o1 = y * wm21;
        #pragma unroll
        for (int off = 32; off > 0; off >>= 1) {
            o0 += __shfl_down(o0, off);
            o1 += __shfl_down(o1, off);
        }
        if (lane == 0) {
            out[wid * 2 + 0] = o0 + bm20;
            out[wid * 2 + 1] = o1 + bm21;
        }
    }
}

extern "C" void kernel_launch(void* const* d_in, const int* in_sizes, int n_in,
                              void* d_out, int out_size, void* d_ws, size_t ws_size,
                              hipStream_t stream)
{
    const float* feature = (const float*)d_in[0];
    const int*   src     = (const int*)d_in[1];
    const int*   dst     = (const int*)d_in[2];
    const float* W1      = (const float*)d_in[3];
    const float* b1      = (const float*)d_in[4];
    const float* W2      = (const float*)d_in[5];
    const float* b2      = (const float*)d_in[6];
    const float* thetas  = (const float*)d_in[7];
    const float* Wm1     = (const float*)d_in[8];
    const float* bm1     = (const float*)d_in[9];
    const float* Wm2     = (const float*)d_in[10];
    const float* bm2     = (const float*)d_in[11];
    float* out = (float*)d_out;

    const size_t NH = (size_t)N_NODES * H_FEATS;   // 6.4M floats
    const int NPAD = 100352;
    float* dinv   = (float*)d_ws;                   // N
    int*   degi   = (int*)(dinv + NPAD);            // N
    int*   rowp   = degi + NPAD;                    // N+1
    int*   bsums  = rowp + NPAD;                    // 512
    int*   cursor = bsums + 512;                    // N
    int2*  epack  = (int2*)(cursor + NPAD);         // E int2
    float* H      = (float*)(epack + N_EDGES);      // N x 64
    float* T0     = H + NH;                         // N x 64
    float* T1     = T0 + NH;                        // N x 64
    float* Weff   = T1 + NH;                        // 16384
    // total ws use ≈ 93 MB

    hipMemsetAsync(degi,   0, N_NODES * sizeof(int), stream);
    hipMemsetAsync(cursor, 0, N_NODES * sizeof(int), stream);

    hist_kernel<<<1024, 256, 0, stream>>>(dst, degi);
    dinv_kernel<<<(N_NODES + 255) / 256, 256, 0, stream>>>(degi, dinv);
    scan1_kernel<<<SCAN_BLOCKS, 256, 0, stream>>>(degi, rowp, bsums);
    scan2_kernel<<<1, 512, 0, stream>>>(bsums);
    scan3_kernel<<<SCAN_BLOCKS, 256, 0, stream>>>(rowp, bsums);
    fill_kernel<<<2048, 256, 0, stream>>>(src, dst, rowp, dinv, cursor, epack);

    weff_kernel<<<64, 256, 0, stream>>>(thetas, Wm1, Weff);
    trunk_kernel<<<1563, 256, 0, stream>>>(feature, W1, b1, W2, b2,
                                           Weff + 3 * 4096, H, T0);

    // Horner: y = c0 + L(c1 + L(c2 + L*c3)), c_k = H @ Weff[k]
    ghorner_kernel<<<3125, 256, 0, stream>>>(T0, H, rowp, epack, dinv,
                                             Weff + 2 * 4096, T1);
    ghorner_kernel<<<3125, 256, 0, stream>>>(T1, H, rowp, epack, dinv,
                                             Weff + 1 * 4096, T0);
    ghfinal_kernel<<<3125, 256, 0, stream>>>(T0, H, rowp, epack, dinv,
                                             Weff, Wm2, bm1, bm2, out);
}

// Round 9
// 449.359 us; speedup vs baseline: 1.3304x; 1.3304x over previous
//
#include <hip/hip_runtime.h>
#include <hip/hip_fp16.h>
#include <math.h>

#define N_NODES 100000
#define N_EDGES 1600000
#define IN_FEATS 128
#define H_FEATS 64
#define SCAN_BLOCKS 391   // ceil(100000/256)

// ---------------- int degree histogram ----------------
__global__ __launch_bounds__(256) void hist_kernel(const int* __restrict__ dst,
                                                   int* __restrict__ degi) {
    int tid = blockIdx.x * 256 + threadIdx.x;
    int stride = gridDim.x * 256;
    for (int e = tid; e < N_EDGES; e += stride)
        atomicAdd(&degi[dst[e]], 1);
}

// degi -> dinv = 1/sqrt(max(deg,1))
__global__ __launch_bounds__(256) void dinv_kernel(const int* __restrict__ degi,
                                                   float* __restrict__ dinv) {
    int i = blockIdx.x * 256 + threadIdx.x;
    if (i < N_NODES) dinv[i] = rsqrtf(fmaxf((float)degi[i], 1.0f));
}

// ---------------- 3-kernel exclusive scan of degi -> rowp ----------------
__global__ __launch_bounds__(256) void scan1_kernel(const int* __restrict__ degi,
                                                    int* __restrict__ rowp,
                                                    int* __restrict__ bsums) {
    __shared__ int tmp[256];
    int i = blockIdx.x * 256 + threadIdx.x;
    int v = (i < N_NODES) ? degi[i] : 0;
    tmp[threadIdx.x] = v;
    __syncthreads();
    #pragma unroll
    for (int off = 1; off < 256; off <<= 1) {
        int t = (threadIdx.x >= off) ? tmp[threadIdx.x - off] : 0;
        __syncthreads();
        tmp[threadIdx.x] += t;
        __syncthreads();
    }
    if (i < N_NODES) rowp[i] = tmp[threadIdx.x] - v;
    if (threadIdx.x == 255) bsums[blockIdx.x] = tmp[255];
}

__global__ __launch_bounds__(512) void scan2_kernel(int* __restrict__ bsums) {
    __shared__ int tmp[512];
    int t = threadIdx.x;
    int v = (t < SCAN_BLOCKS) ? bsums[t] : 0;
    tmp[t] = v;
    __syncthreads();
    #pragma unroll
    for (int off = 1; off < 512; off <<= 1) {
        int x = (t >= off) ? tmp[t - off] : 0;
        __syncthreads();
        tmp[t] += x;
        __syncthreads();
    }
    if (t < SCAN_BLOCKS) bsums[t] = tmp[t] - v;
}

__global__ __launch_bounds__(256) void scan3_kernel(int* __restrict__ rowp,
                                                    const int* __restrict__ bsums) {
    int i = blockIdx.x * 256 + threadIdx.x;
    if (i < N_NODES) rowp[i] += bsums[blockIdx.x];
    if (i == N_NODES) rowp[N_NODES] = N_EDGES;
}

// ---------------- fill CSR slots: single packed 8B write per edge ----------------
__global__ __launch_bounds__(256) void fill_kernel(const int* __restrict__ src,
                                                   const int* __restrict__ dst,
                                                   const int* __restrict__ rowp,
                                                   const float* __restrict__ dinv,
                                                   int* __restrict__ cursor,
                                                   int2* __restrict__ epack) {
    int tid = blockIdx.x * 256 + threadIdx.x;
    int stride = gridDim.x * 256;
    for (int e = tid; e < N_EDGES; e += stride) {
        int d = dst[e];
        int s = src[e];
        int slot = rowp[d] + atomicAdd(&cursor[d], 1);
        epack[slot] = make_int2(s, __float_as_int(dinv[s]));
    }
}

// ---------------- Weff[k][i][j] = sum_c thetas[c][k] * Wm1[c*64+i][j] ----------------
__global__ __launch_bounds__(256) void weff_kernel(const float* __restrict__ thetas,
                                                   const float* __restrict__ Wm1,
                                                   float* __restrict__ Weff) {
    int t = blockIdx.x * 256 + threadIdx.x;  // 16384 total
    int k = t >> 12, ij = t & 4095, i = ij >> 6, j = ij & 63;
    float acc = 0.f;
    #pragma unroll
    for (int c = 0; c < 3; ++c)
        acc = fmaf(thetas[c * 4 + k], Wm1[(c * 64 + i) * 64 + j], acc);
    Weff[t] = acc;
}

// ---------------- trunk: h = relu(relu(X@W1+b1)@W2+b2) -> half table L0h ----------------
// 64 rows/block, 4 batches of 16. K split across 4 waves; weights in VGPRs;
// activations LDS-staged flat (conflict-free). fp32 compute, half store.
__global__ __launch_bounds__(256) void trunk_kernel(
    const float* __restrict__ X, const float* __restrict__ W1, const float* __restrict__ b1,
    const float* __restrict__ W2, const float* __restrict__ b2, __half* __restrict__ H)
{
    __shared__ float stage[16][IN_FEATS];   // 8 KB = 512 float4
    __shared__ float part[4][16][64];       // 16 KB
    __shared__ float h1s[16][64];           // 4 KB
    int t = threadIdx.x;
    int wv = __builtin_amdgcn_readfirstlane(t >> 6);
    int lane = t & 63;
    float w1r[32], w2r[16];
    #pragma unroll
    for (int i = 0; i < 32; ++i) w1r[i] = W1[(wv * 32 + i) * 64 + lane];
    #pragma unroll
    for (int i = 0; i < 16; ++i) w2r[i] = W2[(wv * 16 + i) * 64 + lane];
    float b1v = b1[lane], b2v = b2[lane];
    int srow = t >> 5, sf4 = t & 31;
    float4* st4 = (float4*)stage;

    for (int batch = 0; batch < 4; ++batch) {
        int row0 = blockIdx.x * 64 + batch * 16;
        #pragma unroll
        for (int p = 0; p < 2; ++p) {
            int row = row0 + srow + 8 * p;
            if (row >= N_NODES) row = N_NODES - 1;
            st4[t + 256 * p] =
                ((const float4*)(X + (size_t)row * IN_FEATS))[sf4];
        }
        __syncthreads();
        float acc[16];
        #pragma unroll
        for (int r = 0; r < 16; ++r) {
            const float4* xb = (const float4*)&stage[r][wv * 32];   // uniform -> broadcast
            float a = 0.f, b = 0.f;
            #pragma unroll
            for (int i4 = 0; i4 < 8; i4 += 2) {
                float4 v0 = xb[i4], v1 = xb[i4 + 1];
                a = fmaf(v0.x, w1r[i4 * 4 + 0], a);
                a = fmaf(v0.y, w1r[i4 * 4 + 1], a);
                a = fmaf(v0.z, w1r[i4 * 4 + 2], a);
                a = fmaf(v0.w, w1r[i4 * 4 + 3], a);
                b = fmaf(v1.x, w1r[i4 * 4 + 4], b);
                b = fmaf(v1.y, w1r[i4 * 4 + 5], b);
                b = fmaf(v1.z, w1r[i4 * 4 + 6], b);
                b = fmaf(v1.w, w1r[i4 * 4 + 7], b);
            }
            acc[r] = a + b;
        }
        #pragma unroll
        for (int r = 0; r < 16; ++r) part[wv][r][lane] = acc[r];
        __syncthreads();
        #pragma unroll
        for (int rr = 0; rr < 4; ++rr) {
            int r = wv * 4 + rr;
            float y1 = part[0][r][lane] + part[1][r][lane] +
                       part[2][r][lane] + part[3][r][lane] + b1v;
            h1s[r][lane] = fmaxf(y1, 0.f);
        }
        __syncthreads();
        float acc2[16];
        #pragma unroll
        for (int r = 0; r < 16; ++r) {
            const float4* xb = (const float4*)&h1s[r][wv * 16];     // uniform -> broadcast
            float a = 0.f, b = 0.f;
            #pragma unroll
            for (int i4 = 0; i4 < 4; i4 += 2) {
                float4 v0 = xb[i4], v1 = xb[i4 + 1];
                a = fmaf(v0.x, w2r[i4 * 4 + 0], a);
                a = fmaf(v0.y, w2r[i4 * 4 + 1], a);
                a = fmaf(v0.z, w2r[i4 * 4 + 2], a);
                a = fmaf(v0.w, w2r[i4 * 4 + 3], a);
                b = fmaf(v1.x, w2r[i4 * 4 + 4], b);
                b = fmaf(v1.y, w2r[i4 * 4 + 5], b);
                b = fmaf(v1.z, w2r[i4 * 4 + 6], b);
                b = fmaf(v1.w, w2r[i4 * 4 + 7], b);
            }
            acc2[r] = a + b;
        }
        __syncthreads();
        #pragma unroll
        for (int r = 0; r < 16; ++r) part[wv][r][lane] = acc2[r];
        __syncthreads();
        #pragma unroll
        for (int rr = 0; rr < 4; ++rr) {
            int r = wv * 4 + rr;
            int row = row0 + r;
            float y2 = part[0][r][lane] + part[1][r][lane] +
                       part[2][r][lane] + part[3][r][lane] + b2v;
            if (row < N_NODES) H[(size_t)row * 64 + lane] = __float2half(fmaxf(y2, 0.f));
        }
        __syncthreads();
    }
}

// ---------------- gather pass: Fnew[n] = Fprev[n] - dinv[n]*sum_e w_e*Fprev[s_e]
// half tables (128B row per edge), fp32 accumulate; one wave per node.
__global__ __launch_bounds__(256) void gather_kernel(
    const __half* __restrict__ Fprev, const int* __restrict__ rowp,
    const int2* __restrict__ epack, const float* __restrict__ dinv,
    __half* __restrict__ Fnew)
{
    int wv = __builtin_amdgcn_readfirstlane(threadIdx.x >> 6);
    int wid = blockIdx.x * 4 + wv;   // node id (uniform)
    int lane = threadIdx.x & 63;
    int beg = rowp[wid], end = rowp[wid + 1];
    float acc = 0.0f;
    int j = beg;
    for (; j + 7 < end; j += 8) {
        int2 e0 = epack[j],     e1 = epack[j + 1], e2 = epack[j + 2], e3 = epack[j + 3];
        int2 e4 = epack[j + 4], e5 = epack[j + 5], e6 = epack[j + 6], e7 = epack[j + 7];
        float v0 = __half2float(Fprev[(size_t)e0.x * 64 + lane]);
        float v1 = __half2float(Fprev[(size_t)e1.x * 64 + lane]);
        float v2 = __half2float(Fprev[(size_t)e2.x * 64 + lane]);
        float v3 = __half2float(Fprev[(size_t)e3.x * 64 + lane]);
        float v4 = __half2float(Fprev[(size_t)e4.x * 64 + lane]);
        float v5 = __half2float(Fprev[(size_t)e5.x * 64 + lane]);
        float v6 = __half2float(Fprev[(size_t)e6.x * 64 + lane]);
        float v7 = __half2float(Fprev[(size_t)e7.x * 64 + lane]);
        acc = fmaf(v0, __int_as_float(e0.y), acc);
        acc = fmaf(v1, __int_as_float(e1.y), acc);
        acc = fmaf(v2, __int_as_float(e2.y), acc);
        acc = fmaf(v3, __int_as_float(e3.y), acc);
        acc = fmaf(v4, __int_as_float(e4.y), acc);
        acc = fmaf(v5, __int_as_float(e5.y), acc);
        acc = fmaf(v6, __int_as_float(e6.y), acc);
        acc = fmaf(v7, __int_as_float(e7.y), acc);
    }
    for (; j < end; ++j) {
        int2 e = epack[j];
        acc = fmaf(__half2float(Fprev[(size_t)e.x * 64 + lane]), __int_as_float(e.y), acc);
    }
    float self = __half2float(Fprev[(size_t)wid * 64 + lane]);
    Fnew[(size_t)wid * 64 + lane] = __float2half(self - acc * dinv[wid]);
}

// ---------------- final: out = relu(sum_k Lk @ Weff[k] + bm1) @ Wm2 + bm2 ----------------
// 64 rows/block, 4 batches of 16. Wave wv owns K-slice k=wv, Weff[wv] in 64
// VGPRs. FLAT staging from half tables: thread t stages LDS float4 slot t+256p
// (conflict-free); source k=lane>>4, f0=(lane&15)*4 fixed (tables contiguous).
__global__ __launch_bounds__(256) void final_kernel(
    const __half* __restrict__ L0h,
    const float* __restrict__ Weff, const float* __restrict__ Wm2,
    const float* __restrict__ bm1, const float* __restrict__ bm2,
    float* __restrict__ out)
{
    __shared__ float stage[16][4][64];   // 16 KB = 1024 float4: [row][k][feat]
    __shared__ float part[4][16][64];    // 16 KB
    int t = threadIdx.x;
    int wv = __builtin_amdgcn_readfirstlane(t >> 6);
    int lane = t & 63;
    float wreg[64];
    #pragma unroll
    for (int i = 0; i < 64; ++i)
        wreg[i] = Weff[wv * 4096 + i * 64 + lane];
    float b1v = bm1[lane];
    float wm20 = Wm2[lane * 2 + 0], wm21 = Wm2[lane * 2 + 1];
    float bm20 = bm2[0], bm21 = bm2[1];
    const size_t NH = (size_t)N_NODES * 64;
    // per-thread source: matrix k = lane>>4, 4-half chunk f0 = (lane&15)*4
    const __half* sbase = L0h + (size_t)(lane >> 4) * NH + (size_t)(lane & 15) * 4;
    float4* st4 = (float4*)stage;

    for (int batch = 0; batch < 4; ++batch) {
        int row0 = blockIdx.x * 64 + batch * 16;
        #pragma unroll
        for (int p = 0; p < 4; ++p) {
            int row = row0 + wv + 4 * p;
            if (row >= N_NODES) row = N_NODES - 1;
            uint2 raw = *(const uint2*)(sbase + (size_t)row * 64);
            __half2 h01 = *reinterpret_cast<const __half2*>(&raw.x);
            __half2 h23 = *reinterpret_cast<const __half2*>(&raw.y);
            float2 f01 = __half22float2(h01);
            float2 f23 = __half22float2(h23);
            st4[t + 256 * p] = make_float4(f01.x, f01.y, f23.x, f23.y);
        }
        __syncthreads();
        float acc[16];
        #pragma unroll
        for (int r = 0; r < 16; ++r) {
            const float4* xb = (const float4*)&stage[r][wv][0];   // uniform -> broadcast
            float a = 0.f, b = 0.f;
            #pragma unroll
            for (int i4 = 0; i4 < 16; i4 += 2) {
                float4 v0 = xb[i4], v1 = xb[i4 + 1];
                a = fmaf(v0.x, wreg[i4 * 4 + 0], a);
                a = fmaf(v0.y, wreg[i4 * 4 + 1], a);
                a = fmaf(v0.z, wreg[i4 * 4 + 2], a);
                a = fmaf(v0.w, wreg[i4 * 4 + 3], a);
                b = fmaf(v1.x, wreg[i4 * 4 + 4], b);
                b = fmaf(v1.y, wreg[i4 * 4 + 5], b);
                b = fmaf(v1.z, wreg[i4 * 4 + 6], b);
                b = fmaf(v1.w, wreg[i4 * 4 + 7], b);
            }
            acc[r] = a + b;
        }
        #pragma unroll
        for (int r = 0; r < 16; ++r) part[wv][r][lane] = acc[r];
        __syncthreads();
        #pragma unroll
        for (int rr = 0; rr < 4; ++rr) {
            int r = wv * 4 + rr;
            int row = row0 + r;
            float y = part[0][r][lane] + part[1][r][lane] +
                      part[2][r][lane] + part[3][r][lane] + b1v;
            y = fmaxf(y, 0.f);
            float o0 = y * wm20;
            float o1 = y * wm21;
            #pragma unroll
            for (int off = 32; off > 0; off >>= 1) {
                o0 += __shfl_down(o0, off);
                o1 += __shfl_down(o1, off);
            }
            if (lane == 0 && row < N_NODES) {
                out[row * 2 + 0] = o0 + bm20;
                out[row * 2 + 1] = o1 + bm21;
            }
        }
        __syncthreads();
    }
}

extern "C" void kernel_launch(void* const* d_in, const int* in_sizes, int n_in,
                              void* d_out, int out_size, void* d_ws, size_t ws_size,
                              hipStream_t stream)
{
    const float* feature = (const float*)d_in[0];
    const int*   src     = (const int*)d_in[1];
    const int*   dst     = (const int*)d_in[2];
    const float* W1      = (const float*)d_in[3];
    const float* b1      = (const float*)d_in[4];
    const float* W2      = (const float*)d_in[5];
    const float* b2      = (const float*)d_in[6];
    const float* thetas  = (const float*)d_in[7];
    const float* Wm1     = (const float*)d_in[8];
    const float* bm1     = (const float*)d_in[9];
    const float* Wm2     = (const float*)d_in[10];
    const float* bm2     = (const float*)d_in[11];
    float* out = (float*)d_out;

    const size_t NH = (size_t)N_NODES * H_FEATS;   // 6.4M elems
    const int NPAD = 100352;
    float*  dinv   = (float*)d_ws;                  // N
    int*    degi   = (int*)(dinv + NPAD);           // N
    int*    rowp   = degi + NPAD;                   // N+1
    int*    bsums  = rowp + NPAD;                   // 512
    int*    cursor = bsums + 512;                   // N
    int2*   epack  = (int2*)(cursor + NPAD);        // E int2
    __half* Lh     = (__half*)(epack + N_EDGES);    // 4 x NH halfs, contiguous
    float*  Weff   = (float*)(Lh + 4 * NH);         // 16384 floats
    // total ws use ≈ 66 MB

    hipMemsetAsync(degi,   0, N_NODES * sizeof(int), stream);
    hipMemsetAsync(cursor, 0, N_NODES * sizeof(int), stream);

    hist_kernel<<<1024, 256, 0, stream>>>(dst, degi);
    dinv_kernel<<<(N_NODES + 255) / 256, 256, 0, stream>>>(degi, dinv);
    scan1_kernel<<<SCAN_BLOCKS, 256, 0, stream>>>(degi, rowp, bsums);
    scan2_kernel<<<1, 512, 0, stream>>>(bsums);
    scan3_kernel<<<SCAN_BLOCKS, 256, 0, stream>>>(rowp, bsums);
    fill_kernel<<<2048, 256, 0, stream>>>(src, dst, rowp, dinv, cursor, epack);

    weff_kernel<<<64, 256, 0, stream>>>(thetas, Wm1, Weff);
    trunk_kernel<<<1563, 256, 0, stream>>>(feature, W1, b1, W2, b2, Lh);  // -> L0h

    for (int k = 1; k <= 3; ++k)
        gather_kernel<<<25000, 256, 0, stream>>>(Lh + (size_t)(k - 1) * NH, rowp, epack,
                                                 dinv, Lh + (size_t)k * NH);

    final_kernel<<<1563, 256, 0, stream>>>(Lh, Weff, Wm2, bm1, bm2, out);
}

// Round 10
// 382.924 us; speedup vs baseline: 1.5612x; 1.1735x over previous
//
#include <hip/hip_runtime.h>
#include <hip/hip_fp16.h>
#include <math.h>

#define N_NODES 100000
#define N_EDGES 1600000
#define IN_FEATS 128
#define H_FEATS 64
#define SCAN_BLOCKS 391   // ceil(100000/256)

typedef _Float16 f16x8 __attribute__((ext_vector_type(8)));
typedef float f32x4 __attribute__((ext_vector_type(4)));

// ---------------- int degree histogram ----------------
__global__ __launch_bounds__(256) void hist_kernel(const int* __restrict__ dst,
                                                   int* __restrict__ degi) {
    int tid = blockIdx.x * 256 + threadIdx.x;
    int stride = gridDim.x * 256;
    for (int e = tid; e < N_EDGES; e += stride)
        atomicAdd(&degi[dst[e]], 1);
}

// degi -> dinv = 1/sqrt(max(deg,1))
__global__ __launch_bounds__(256) void dinv_kernel(const int* __restrict__ degi,
                                                   float* __restrict__ dinv) {
    int i = blockIdx.x * 256 + threadIdx.x;
    if (i < N_NODES) dinv[i] = rsqrtf(fmaxf((float)degi[i], 1.0f));
}

// ---------------- 3-kernel exclusive scan of degi -> rowp ----------------
__global__ __launch_bounds__(256) void scan1_kernel(const int* __restrict__ degi,
                                                    int* __restrict__ rowp,
                                                    int* __restrict__ bsums) {
    __shared__ int tmp[256];
    int i = blockIdx.x * 256 + threadIdx.x;
    int v = (i < N_NODES) ? degi[i] : 0;
    tmp[threadIdx.x] = v;
    __syncthreads();
    #pragma unroll
    for (int off = 1; off < 256; off <<= 1) {
        int t = (threadIdx.x >= off) ? tmp[threadIdx.x - off] : 0;
        __syncthreads();
        tmp[threadIdx.x] += t;
        __syncthreads();
    }
    if (i < N_NODES) rowp[i] = tmp[threadIdx.x] - v;
    if (threadIdx.x == 255) bsums[blockIdx.x] = tmp[255];
}

__global__ __launch_bounds__(512) void scan2_kernel(int* __restrict__ bsums) {
    __shared__ int tmp[512];
    int t = threadIdx.x;
    int v = (t < SCAN_BLOCKS) ? bsums[t] : 0;
    tmp[t] = v;
    __syncthreads();
    #pragma unroll
    for (int off = 1; off < 512; off <<= 1) {
        int x = (t >= off) ? tmp[t - off] : 0;
        __syncthreads();
        tmp[t] += x;
        __syncthreads();
    }
    if (t < SCAN_BLOCKS) bsums[t] = tmp[t] - v;
}

__global__ __launch_bounds__(256) void scan3_kernel(int* __restrict__ rowp,
                                                    const int* __restrict__ bsums) {
    int i = blockIdx.x * 256 + threadIdx.x;
    if (i < N_NODES) rowp[i] += bsums[blockIdx.x];
    if (i == N_NODES) rowp[N_NODES] = N_EDGES;
}

// ---------------- fill CSR slots: single packed 8B write per edge ----------------
__global__ __launch_bounds__(256) void fill_kernel(const int* __restrict__ src,
                                                   const int* __restrict__ dst,
                                                   const int* __restrict__ rowp,
                                                   const float* __restrict__ dinv,
                                                   int* __restrict__ cursor,
                                                   int2* __restrict__ epack) {
    int tid = blockIdx.x * 256 + threadIdx.x;
    int stride = gridDim.x * 256;
    for (int e = tid; e < N_EDGES; e += stride) {
        int d = dst[e];
        int s = src[e];
        int slot = rowp[d] + atomicAdd(&cursor[d], 1);
        epack[slot] = make_int2(s, __float_as_int(dinv[s]));
    }
}

// ---------------- Bpack: Weff collapsed + fp16 + MFMA B-fragment order ----------------
// Fragment (s, nt): lane l, elem j holds B[k = 32s + (l>>4)*8 + j][n = nt*16 + (l&15)]
// where B[k][n] = Weff[q = k>>6][f = k&63][n] = sum_c thetas[c][q] * Wm1[c*64+f][n].
__global__ __launch_bounds__(256) void wpack_kernel(const float* __restrict__ thetas,
                                                    const float* __restrict__ Wm1,
                                                    __half* __restrict__ Bpack) {
    int u = blockIdx.x * 256 + threadIdx.x;   // 16384 total
    int j = u & 7, lane = (u >> 3) & 63, frag = u >> 9;
    int nt = frag & 3, s = frag >> 2;
    int k = 32 * s + ((lane >> 4) << 3) + j;
    int q = k >> 6, f = k & 63;
    int n = nt * 16 + (lane & 15);
    float acc = 0.f;
    #pragma unroll
    for (int c = 0; c < 3; ++c)
        acc = fmaf(thetas[c * 4 + q], Wm1[(c * 64 + f) * 64 + n], acc);
    Bpack[u] = __float2half(acc);
}

// ---------------- trunk: h = relu(relu(X@W1+b1)@W2+b2) -> half table L0h ----------------
__global__ __launch_bounds__(256) void trunk_kernel(
    const float* __restrict__ X, const float* __restrict__ W1, const float* __restrict__ b1,
    const float* __restrict__ W2, const float* __restrict__ b2, __half* __restrict__ H)
{
    __shared__ float stage[16][IN_FEATS];   // 8 KB = 512 float4
    __shared__ float part[4][16][64];       // 16 KB
    __shared__ float h1s[16][64];           // 4 KB
    int t = threadIdx.x;
    int wv = __builtin_amdgcn_readfirstlane(t >> 6);
    int lane = t & 63;
    float w1r[32], w2r[16];
    #pragma unroll
    for (int i = 0; i < 32; ++i) w1r[i] = W1[(wv * 32 + i) * 64 + lane];
    #pragma unroll
    for (int i = 0; i < 16; ++i) w2r[i] = W2[(wv * 16 + i) * 64 + lane];
    float b1v = b1[lane], b2v = b2[lane];
    int srow = t >> 5, sf4 = t & 31;
    float4* st4 = (float4*)stage;

    for (int batch = 0; batch < 4; ++batch) {
        int row0 = blockIdx.x * 64 + batch * 16;
        #pragma unroll
        for (int p = 0; p < 2; ++p) {
            int row = row0 + srow + 8 * p;
            if (row >= N_NODES) row = N_NODES - 1;
            st4[t + 256 * p] =
                ((const float4*)(X + (size_t)row * IN_FEATS))[sf4];
        }
        __syncthreads();
        float acc[16];
        #pragma unroll
        for (int r = 0; r < 16; ++r) {
            const float4* xb = (const float4*)&stage[r][wv * 32];   // uniform -> broadcast
            float a = 0.f, b = 0.f;
            #pragma unroll
            for (int i4 = 0; i4 < 8; i4 += 2) {
                float4 v0 = xb[i4], v1 = xb[i4 + 1];
                a = fmaf(v0.x, w1r[i4 * 4 + 0], a);
                a = fmaf(v0.y, w1r[i4 * 4 + 1], a);
                a = fmaf(v0.z, w1r[i4 * 4 + 2], a);
                a = fmaf(v0.w, w1r[i4 * 4 + 3], a);
                b = fmaf(v1.x, w1r[i4 * 4 + 4], b);
                b = fmaf(v1.y, w1r[i4 * 4 + 5], b);
                b = fmaf(v1.z, w1r[i4 * 4 + 6], b);
                b = fmaf(v1.w, w1r[i4 * 4 + 7], b);
            }
            acc[r] = a + b;
        }
        #pragma unroll
        for (int r = 0; r < 16; ++r) part[wv][r][lane] = acc[r];
        __syncthreads();
        #pragma unroll
        for (int rr = 0; rr < 4; ++rr) {
            int r = wv * 4 + rr;
            float y1 = part[0][r][lane] + part[1][r][lane] +
                       part[2][r][lane] + part[3][r][lane] + b1v;
            h1s[r][lane] = fmaxf(y1, 0.f);
        }
        __syncthreads();
        float acc2[16];
        #pragma unroll
        for (int r = 0; r < 16; ++r) {
            const float4* xb = (const float4*)&h1s[r][wv * 16];     // uniform -> broadcast
            float a = 0.f, b = 0.f;
            #pragma unroll
            for (int i4 = 0; i4 < 4; i4 += 2) {
                float4 v0 = xb[i4], v1 = xb[i4 + 1];
                a = fmaf(v0.x, w2r[i4 * 4 + 0], a);
                a = fmaf(v0.y, w2r[i4 * 4 + 1], a);
                a = fmaf(v0.z, w2r[i4 * 4 + 2], a);
                a = fmaf(v0.w, w2r[i4 * 4 + 3], a);
                b = fmaf(v1.x, w2r[i4 * 4 + 4], b);
                b = fmaf(v1.y, w2r[i4 * 4 + 5], b);
                b = fmaf(v1.z, w2r[i4 * 4 + 6], b);
                b = fmaf(v1.w, w2r[i4 * 4 + 7], b);
            }
            acc2[r] = a + b;
        }
        __syncthreads();
        #pragma unroll
        for (int r = 0; r < 16; ++r) part[wv][r][lane] = acc2[r];
        __syncthreads();
        #pragma unroll
        for (int rr = 0; rr < 4; ++rr) {
            int r = wv * 4 + rr;
            int row = row0 + r;
            float y2 = part[0][r][lane] + part[1][r][lane] +
                       part[2][r][lane] + part[3][r][lane] + b2v;
            if (row < N_NODES) H[(size_t)row * 64 + lane] = __float2half(fmaxf(y2, 0.f));
        }
        __syncthreads();
    }
}

// ---------------- gather pass: Fnew[n] = Fprev[n] - dinv[n]*sum_e w_e*Fprev[s_e]
__global__ __launch_bounds__(256) void gather_kernel(
    const __half* __restrict__ Fprev, const int* __restrict__ rowp,
    const int2* __restrict__ epack, const float* __restrict__ dinv,
    __half* __restrict__ Fnew)
{
    int wv = __builtin_amdgcn_readfirstlane(threadIdx.x >> 6);
    int wid = blockIdx.x * 4 + wv;   // node id (uniform)
    int lane = threadIdx.x & 63;
    int beg = rowp[wid], end = rowp[wid + 1];
    float acc = 0.0f;
    int j = beg;
    for (; j + 7 < end; j += 8) {
        int2 e0 = epack[j],     e1 = epack[j + 1], e2 = epack[j + 2], e3 = epack[j + 3];
        int2 e4 = epack[j + 4], e5 = epack[j + 5], e6 = epack[j + 6], e7 = epack[j + 7];
        float v0 = __half2float(Fprev[(size_t)e0.x * 64 + lane]);
        float v1 = __half2float(Fprev[(size_t)e1.x * 64 + lane]);
        float v2 = __half2float(Fprev[(size_t)e2.x * 64 + lane]);
        float v3 = __half2float(Fprev[(size_t)e3.x * 64 + lane]);
        float v4 = __half2float(Fprev[(size_t)e4.x * 64 + lane]);
        float v5 = __half2float(Fprev[(size_t)e5.x * 64 + lane]);
        float v6 = __half2float(Fprev[(size_t)e6.x * 64 + lane]);
        float v7 = __half2float(Fprev[(size_t)e7.x * 64 + lane]);
        acc = fmaf(v0, __int_as_float(e0.y), acc);
        acc = fmaf(v1, __int_as_float(e1.y), acc);
        acc = fmaf(v2, __int_as_float(e2.y), acc);
        acc = fmaf(v3, __int_as_float(e3.y), acc);
        acc = fmaf(v4, __int_as_float(e4.y), acc);
        acc = fmaf(v5, __int_as_float(e5.y), acc);
        acc = fmaf(v6, __int_as_float(e6.y), acc);
        acc = fmaf(v7, __int_as_float(e7.y), acc);
    }
    for (; j < end; ++j) {
        int2 e = epack[j];
        acc = fmaf(__half2float(Fprev[(size_t)e.x * 64 + lane]), __int_as_float(e.y), acc);
    }
    float self = __half2float(Fprev[(size_t)wid * 64 + lane]);
    Fnew[(size_t)wid * 64 + lane] = __float2half(self - acc * dinv[wid]);
}

// ---------------- final (MFMA): out = relu(A@B + bm1) @ Wm2 + bm2 ----------------
// A[100000 x 256] fp16 = [L0|L1|L2|L3] column-blocked (Lh contiguous);
// B[256 x 64] fp16 pre-packed in fragment order (Bpack).
// One wave per 16-row tile, 4 tiles per wave. Inner: 8 A-loads + 32 MFMA.
// A-frag (step s): lane l holds A[row0+(l&15)][k=32s+(l>>4)*8+j], j=0..7
//   -> global: Lh + (s>>1)*NH + row*64 + 32*(s&1) + (l>>4)*8   (16B load)
// D: col n = nt*16 + (l&15), row = row0 + (l>>4)*4 + reg   [m89 layout]
__global__ __launch_bounds__(256) void final_mfma_kernel(
    const __half* __restrict__ L0h, const __half* __restrict__ Bpack,
    const float* __restrict__ Wm2, const float* __restrict__ bm1,
    const float* __restrict__ bm2, float* __restrict__ out)
{
    const size_t NH = (size_t)N_NODES * 64;
    int t = threadIdx.x;
    int wv = t >> 6;
    int lane = t & 63;
    int gw = blockIdx.x * 4 + wv;          // 1564 waves

    // preload all 32 B fragments (128 VGPRs)
    const f16x8* bp = (const f16x8*)Bpack;
    f16x8 b[4][8];
    #pragma unroll
    for (int s = 0; s < 8; ++s)
        #pragma unroll
        for (int nt = 0; nt < 4; ++nt)
            b[nt][s] = bp[(s * 4 + nt) * 64 + lane];

    // per-lane head constants: n = nt*16 + (lane&15)
    float bm1v[4], w20[4], w21[4];
    #pragma unroll
    for (int nt = 0; nt < 4; ++nt) {
        int n = nt * 16 + (lane & 15);
        bm1v[nt] = bm1[n];
        w20[nt] = Wm2[n * 2 + 0];
        w21[nt] = Wm2[n * 2 + 1];
    }
    float bm20 = bm2[0], bm21 = bm2[1];

    for (int u = 0; u < 4; ++u) {
        int tile = gw * 4 + u;
        if (tile >= 6250) break;           // 6250 * 16 = 100000 exactly
        int row0 = tile * 16;
        const __half* abase = L0h + (size_t)(row0 + (lane & 15)) * 64 + ((lane >> 4) << 3);
        f16x8 a[8];
        #pragma unroll
        for (int s = 0; s < 8; ++s)
            a[s] = *(const f16x8*)(abase + (size_t)(s >> 1) * NH + 32 * (s & 1));
        f32x4 acc[4];
        #pragma unroll
        for (int nt = 0; nt < 4; ++nt) acc[nt] = (f32x4){0.f, 0.f, 0.f, 0.f};
        #pragma unroll
        for (int s = 0; s < 8; ++s)
            #pragma unroll
            for (int nt = 0; nt < 4; ++nt)
                acc[nt] = __builtin_amdgcn_mfma_f32_16x16x32_f16(a[s], b[nt][s], acc[nt], 0, 0, 0);
        // epilogue: relu + bm1, head GEMV, reduce over n within 16-lane groups
        float o0[4], o1[4];
        #pragma unroll
        for (int reg = 0; reg < 4; ++reg) { o0[reg] = 0.f; o1[reg] = 0.f; }
        #pragma unroll
        for (int nt = 0; nt < 4; ++nt)
            #pragma unroll
            for (int reg = 0; reg < 4; ++reg) {
                float v = fmaxf(acc[nt][reg] + bm1v[nt], 0.f);
                o0[reg] = fmaf(v, w20[nt], o0[reg]);
                o1[reg] = fmaf(v, w21[nt], o1[reg]);
            }
        #pragma unroll
        for (int reg = 0; reg < 4; ++reg) {
            #pragma unroll
            for (int m = 8; m > 0; m >>= 1) {
                o0[reg] += __shfl_xor(o0[reg], m);
                o1[reg] += __shfl_xor(o1[reg], m);
            }
        }
        if ((lane & 15) == 0) {
            int rbase = row0 + (lane >> 4) * 4;
            #pragma unroll
            for (int reg = 0; reg < 4; ++reg) {
                out[(rbase + reg) * 2 + 0] = o0[reg] + bm20;
                out[(rbase + reg) * 2 + 1] = o1[reg] + bm21;
            }
        }
    }
}

extern "C" void kernel_launch(void* const* d_in, const int* in_sizes, int n_in,
                              void* d_out, int out_size, void* d_ws, size_t ws_size,
                              hipStream_t stream)
{
    const float* feature = (const float*)d_in[0];
    const int*   src     = (const int*)d_in[1];
    const int*   dst     = (const int*)d_in[2];
    const float* W1      = (const float*)d_in[3];
    const float* b1      = (const float*)d_in[4];
    const float* W2      = (const float*)d_in[5];
    const float* b2      = (const float*)d_in[6];
    const float* thetas  = (const float*)d_in[7];
    const float* Wm1     = (const float*)d_in[8];
    const float* bm1     = (const float*)d_in[9];
    const float* Wm2     = (const float*)d_in[10];
    const float* bm2     = (const float*)d_in[11];
    float* out = (float*)d_out;

    const size_t NH = (size_t)N_NODES * H_FEATS;   // 6.4M elems
    const int NPAD = 100352;
    float*  dinv   = (float*)d_ws;                  // N
    int*    degi   = (int*)(dinv + NPAD);           // N
    int*    rowp   = degi + NPAD;                   // N+1
    int*    bsums  = rowp + NPAD;                   // 512
    int*    cursor = bsums + 512;                   // N
    int2*   epack  = (int2*)(cursor + NPAD);        // E int2
    __half* Lh     = (__half*)(epack + N_EDGES);    // 4 x NH halfs, contiguous
    __half* Bpack  = Lh + 4 * NH;                   // 16384 halfs (32 KB)
    // total ws use ≈ 66 MB

    hipMemsetAsync(degi,   0, N_NODES * sizeof(int), stream);
    hipMemsetAsync(cursor, 0, N_NODES * sizeof(int), stream);

    hist_kernel<<<1024, 256, 0, stream>>>(dst, degi);
    dinv_kernel<<<(N_NODES + 255) / 256, 256, 0, stream>>>(degi, dinv);
    scan1_kernel<<<SCAN_BLOCKS, 256, 0, stream>>>(degi, rowp, bsums);
    scan2_kernel<<<1, 512, 0, stream>>>(bsums);
    scan3_kernel<<<SCAN_BLOCKS, 256, 0, stream>>>(rowp, bsums);
    fill_kernel<<<2048, 256, 0, stream>>>(src, dst, rowp, dinv, cursor, epack);

    wpack_kernel<<<64, 256, 0, stream>>>(thetas, Wm1, Bpack);
    trunk_kernel<<<1563, 256, 0, stream>>>(feature, W1, b1, W2, b2, Lh);  // -> L0h

    for (int k = 1; k <= 3; ++k)
        gather_kernel<<<25000, 256, 0, stream>>>(Lh + (size_t)(k - 1) * NH, rowp, epack,
                                                 dinv, Lh + (size_t)k * NH);

    final_mfma_kernel<<<391, 256, 0, stream>>>(Lh, Bpack, Wm2, bm1, bm2, out);
}